// Round 4
// baseline (1844.470 us; speedup 1.0000x reference)
//
#include <hip/hip_runtime.h>

typedef unsigned short u16;
typedef __attribute__((ext_vector_type(8))) short short8;
typedef __attribute__((ext_vector_type(4))) float f32x4;

__device__ __forceinline__ float bf2f(u16 x){
  union { unsigned u; float f; } c; c.u = ((unsigned)x) << 16; return c.f;
}
__device__ __forceinline__ u16 f2bf(float f){
  union { float f; unsigned u; } c; c.f = f;
  unsigned u = c.u;
  return (u16)((u + 0x7FFFu + ((u >> 16) & 1u)) >> 16);
}
__device__ __forceinline__ unsigned pk2(float a, float b){
  return (unsigned)f2bf(a) | ((unsigned)f2bf(b) << 16);
}
__device__ __forceinline__ void hilo(float v, u16& hi, u16& lo){
  hi = f2bf(v); lo = f2bf(v - bf2f(hi));
}

__device__ __forceinline__ void gload16(const void* g, void* l){
  __builtin_amdgcn_global_load_lds(
    (const __attribute__((address_space(1))) void*)g,
    (__attribute__((address_space(3))) void*)l, 16, 0, 0);
}

// ---------- cls token ----------
__global__ void k_cls(const float* cls, float* h){
  int b = blockIdx.x, t = threadIdx.x;
  for (int c=t; c<512; c+=256)
    h[((long)b*8192+191)*512 + c] = cls[c];
}

// ---------- weight convert + transpose: W f32 [K][N] -> wT bf16 [N][K] ----------
__global__ void k_cvtT(const float* Wm, u16* wT, int K, int N){
  __shared__ float tile[32][33];
  int n0 = blockIdx.x*32, k0 = blockIdx.y*32;
  int x = threadIdx.x & 31, y = threadIdx.x >> 5;
  #pragma unroll
  for (int p=0;p<4;p++) tile[y+8*p][x] = Wm[(long)(k0+y+8*p)*N + n0 + x];
  __syncthreads();
  #pragma unroll
  for (int p=0;p<4;p++) wT[(long)(n0+y+8*p)*K + k0 + x] = f2bf(tile[x][y+8*p]);
}

// ---------- MFMA GEMM: 128x128 tile, BK=32, 4 waves (grid: x=ntile, y=mtile) ----------
template<int MODE>
__launch_bounds__(256)
__global__ void k_gemm(const void* Av, const u16* Bt, const float* bias,
                       float* hout, float* qo, float* ko, float* vo,
                       int M, int N, int K){
  __shared__ __align__(16) u16 As[128*32];
  __shared__ __align__(16) u16 Bs[128*32];
  const int tid = threadIdx.x;
  const int wave = tid>>6, lane = tid&63;
  const int m0 = blockIdx.y*128, n0 = blockIdx.x*128;
  const int wr = wave>>1, wc = wave&1;
  f32x4 acc[4][4];
  #pragma unroll
  for (int i=0;i<4;i++)
    #pragma unroll
    for (int j=0;j<4;j++) acc[i][j] = (f32x4){0.f,0.f,0.f,0.f};

  for (int k0=0; k0<K; k0+=32){
    if constexpr (MODE == 0){
      int r = tid>>1, half = tid&1;
      const float* gp = (const float*)Av + (long)(m0+r)*K + k0 + half*16;
      float4 f0 = *(const float4*)(gp+0);
      float4 f1 = *(const float4*)(gp+4);
      float4 f2 = *(const float4*)(gp+8);
      float4 f3 = *(const float4*)(gp+12);
      uint4 pa, pb;
      pa.x = pk2(f0.x,f0.y); pa.y = pk2(f0.z,f0.w);
      pa.z = pk2(f1.x,f1.y); pa.w = pk2(f1.z,f1.w);
      pb.x = pk2(f2.x,f2.y); pb.y = pk2(f2.z,f2.w);
      pb.z = pk2(f3.x,f3.y); pb.w = pk2(f3.z,f3.w);
      uint4* dst = (uint4*)&As[r*32 + half*16];
      dst[0] = pa; dst[1] = pb;
    } else {
      #pragma unroll
      for (int ci=0; ci<2; ++ci){
        int c = wave*2 + ci;
        int r = (c<<4) + (lane>>2), kq = lane&3;
        const u16* gp;
        if constexpr (MODE == 1){
          gp = (const u16*)Av + (long)(m0+r)*K + k0 + kq*8;
        } else {
          int rr = m0 + r; int b = rr>>13, pos = rr&8191;
          int cc = k0 + kq*8; int hh = cc>>6, d = cc&63;
          gp = (const u16*)Av + ((long)(b*8+hh)*8192 + pos)*64 + d;
        }
        gload16(gp, &As[c*512]);
      }
    }
    #pragma unroll
    for (int ci=0; ci<2; ++ci){
      int c = wave*2 + ci;
      int r = (c<<4) + (lane>>2), kq = lane&3;
      gload16(Bt + (long)(n0+r)*K + k0 + kq*8, &Bs[c*512]);
    }
    __syncthreads();
    short8 af[4], bf[4];
    int arow = wr*64 + (lane&15);
    int brow = wc*64 + (lane&15);
    int koff = (lane>>4)*8;
    #pragma unroll
    for (int i=0;i<4;i++){
      af[i] = *(const short8*)&As[(arow + i*16)*32 + koff];
      bf[i] = *(const short8*)&Bs[(brow + i*16)*32 + koff];
    }
    #pragma unroll
    for (int i=0;i<4;i++)
      #pragma unroll
      for (int j=0;j<4;j++)
        acc[i][j] = __builtin_amdgcn_mfma_f32_16x16x32_bf16(af[i], bf[j], acc[i][j], 0,0,0);
    __syncthreads();
  }

  const int lr = lane>>4, lc = lane&15;
  if constexpr (MODE == 0){
    #pragma unroll
    for (int j=0;j<4;j++){
      int cb = n0 + wc*64 + j*16 + lc;
      float bb = bias[cb];
      #pragma unroll
      for (int i=0;i<4;i++){
        #pragma unroll
        for (int r=0;r<4;r++){
          int row = m0 + wr*64 + i*16 + lr*4 + r;
          int b = (row >= 8000) ? 1 : 0;
          int tok = row - b*8000;
          hout[((long)(b*8192 + 192 + tok))*512 + cb] = fmaxf(acc[i][j][r] + bb, 0.f);
        }
      }
    }
  } else if constexpr (MODE == 1){
    #pragma unroll
    for (int j=0;j<4;j++){
      int cb = n0 + wc*64 + j*16 + lc;
      int which = cb>>9, head = (cb>>6)&7, d = cb&63;
      float* base = (which==0) ? qo : (which==1 ? ko : vo);
      float scale = (which==0) ? 0.125f : 1.0f;
      #pragma unroll
      for (int i=0;i<4;i++){
        #pragma unroll
        for (int r=0;r<4;r++){
          int row = m0 + wr*64 + i*16 + lr*4 + r;
          int b = row>>13, pos = row&8191;
          base[((long)(b*8+head)*8192 + pos)*64 + d] = acc[i][j][r]*scale;
        }
      }
    }
  } else {
    #pragma unroll
    for (int j=0;j<4;j++){
      int cb = n0 + wc*64 + j*16 + lc;
      float bb = bias[cb];
      #pragma unroll
      for (int i=0;i<4;i++){
        #pragma unroll
        for (int r=0;r<4;r++){
          int row = m0 + wr*64 + i*16 + lr*4 + r;
          int pos = row&8191;
          if (pos >= 191) hout[(long)row*512 + cb] += acc[i][j][r] + bb;
        }
      }
    }
  }
}

// ---------- layernorm: h f32 -> xln bf16 (pad rows -> 0) ----------
__global__ void k_ln(const float* hsrc, const float* g, const float* bt, u16* xlnb){
  int row = blockIdx.x;
  int pos = row & 8191;
  int t = threadIdx.x;
  long base = (long)row*512 + t*2;
  if (pos < 191){ *(unsigned*)&xlnb[base] = 0u; return; }
  float2 x = *(const float2*)(hsrc + base);
  __shared__ float red[4];
  float s = x.x + x.y;
  for (int off=32; off; off>>=1) s += __shfl_down(s, off, 64);
  if ((t&63)==0) red[t>>6]=s;
  __syncthreads();
  float mean = (red[0]+red[1]+red[2]+red[3]) * (1.f/512.f);
  __syncthreads();
  float d0 = x.x-mean, d1 = x.y-mean;
  float ss = d0*d0 + d1*d1;
  for (int off=32; off; off>>=1) ss += __shfl_down(ss, off, 64);
  if ((t&63)==0) red[t>>6]=ss;
  __syncthreads();
  float rstd = rsqrtf((red[0]+red[1]+red[2]+red[3])*(1.f/512.f) + 1e-5f);
  float o0 = d0*rstd*g[t*2]   + bt[t*2];
  float o1 = d1*rstd*g[t*2+1] + bt[t*2+1];
  *(unsigned*)&xlnb[base] = pk2(o0, o1);
}

// ---------- landmark means ----------
__global__ void k_landmark(const float* src, float* dst){
  int g = blockIdx.x, bh = blockIdx.y, d = threadIdx.x;
  const float* p = src + (((long)bh*8192) + g*32)*64 + d;
  float s = 0.f;
  #pragma unroll
  for (int j=0;j<32;j++) s += p[j*64];
  dst[((long)bh*256 + g)*64 + d] = s*(1.f/32.f);
}

// ---------- a2 = softmax(q_l @ k_l^T): f32 + hi/lo N-planes ----------
__launch_bounds__(256)
__global__ void k_a2(const float* qlm, const float* klm, float* a2, u16* a2Nh, u16* a2Nl){
  __shared__ float qls[16][68];
  __shared__ float kls[64][65];
  __shared__ float Sf[16][260];
  __shared__ float red[4];
  int bh = blockIdx.y, rt = blockIdx.x, t = threadIdx.x;
  const float* qp = qlm + ((long)bh*256 + rt*16)*64;
  { int fidx = t*4; int r = fidx>>6, c = fidx&63;
    float4 a = *(const float4*)(qp + fidx);
    qls[r][c]=a.x; qls[r][c+1]=a.y; qls[r][c+2]=a.z; qls[r][c+3]=a.w; }
  const float* kp = klm + (long)bh*16384;
  int cl = t & 63, ig = t >> 6;
  for (int kt=0; kt<4; ++kt){
    __syncthreads();
    for (int l=0;l<4;l++){
      int fidx = (l*256+t)*4; int r = fidx>>6, c = fidx&63;
      float4 a = *(const float4*)(kp + (long)(kt*64+r)*64 + c);
      kls[r][c]=a.x; kls[r][c+1]=a.y; kls[r][c+2]=a.z; kls[r][c+3]=a.w;
    }
    __syncthreads();
    float s0=0,s1=0,s2=0,s3=0;
    #pragma unroll
    for (int d=0;d<64;d++){
      float kv = kls[cl][d];
      s0 += qls[ig*4+0][d]*kv;
      s1 += qls[ig*4+1][d]*kv;
      s2 += qls[ig*4+2][d]*kv;
      s3 += qls[ig*4+3][d]*kv;
    }
    Sf[ig*4+0][kt*64+cl]=s0;
    Sf[ig*4+1][kt*64+cl]=s1;
    Sf[ig*4+2][kt*64+cl]=s2;
    Sf[ig*4+3][kt*64+cl]=s3;
  }
  __syncthreads();
  long ab = ((long)bh*256 + rt*16)*256;
  for (int i=0;i<16;i++){
    float val = Sf[i][t];
    float m = val;
    for (int off=1; off<64; off<<=1) m = fmaxf(m, __shfl_xor(m,off,64));
    if ((t&63)==0) red[t>>6]=m;
    __syncthreads();
    m = fmaxf(fmaxf(red[0],red[1]),fmaxf(red[2],red[3]));
    __syncthreads();
    float e = __expf(val - m);
    float sum = e;
    for (int off=1; off<64; off<<=1) sum += __shfl_xor(sum,off,64);
    if ((t&63)==0) red[t>>6]=sum;
    __syncthreads();
    sum = red[0]+red[1]+red[2]+red[3];
    __syncthreads();
    float o = e/sum;
    long idx = ab + (long)i*256 + t;
    a2[idx] = o;
    u16 hi, lo; hilo(o, hi, lo);
    a2Nh[idx]=hi; a2Nl[idx]=lo;
  }
}

// ---------- pinv denominator ----------
__global__ void k_colrow(const float* a2, float* rc){
  int bh = blockIdx.x, t = threadIdx.x;
  const float* p = a2 + (long)bh*65536;
  float cs=0.f, rs=0.f;
  for (int r=0;r<256;r++) cs += fabsf(p[(long)r*256 + t]);
  for (int c=0;c<256;c++) rs += fabsf(p[(long)t*256 + c]);
  __shared__ float red[4];
  for (int off=32; off; off>>=1) cs = fmaxf(cs, __shfl_down(cs,off,64));
  if ((t&63)==0) red[t>>6]=cs;
  __syncthreads();
  if (t==0) rc[bh] = fmaxf(fmaxf(red[0],red[1]),fmaxf(red[2],red[3]));
  __syncthreads();
  for (int off=32; off; off>>=1) rs = fmaxf(rs, __shfl_down(rs,off,64));
  if ((t&63)==0) red[t>>6]=rs;
  __syncthreads();
  if (t==0) rc[16+bh] = fmaxf(fmaxf(red[0],red[1]),fmaxf(red[2],red[3]));
}
__global__ void k_denom(const float* rc, float* denom){
  float cm=0.f, rm=0.f;
  for (int i=0;i<16;i++){ cm=fmaxf(cm,rc[i]); rm=fmaxf(rm,rc[16+i]); }
  *denom = cm*rm;
}

// ---------- z0 planes: zN = a2^T/denom, zT = a2/denom (hi/lo each) ----------
__global__ void k_z0p(const float* a2, const float* denom,
                      u16* zNh, u16* zNl, u16* zTh, u16* zTl){
  __shared__ float tile[32][33];
  int bh = blockIdx.z;
  int c0 = blockIdx.x*32, r0 = blockIdx.y*32;
  int x = threadIdx.x & 31, y = threadIdx.x >> 5;
  const float* p = a2 + (long)bh*65536;
  float inv = 1.0f / (*denom);
  long zb = (long)bh*65536;
  #pragma unroll
  for (int yy=0; yy<32; yy+=8){
    float vv = p[(long)(r0+y+yy)*256 + c0 + x];
    tile[y+yy][x] = vv;
    float val = vv*inv;
    u16 hi, lo; hilo(val, hi, lo);
    long idx = zb + (long)(r0+y+yy)*256 + c0 + x;
    zTh[idx]=hi; zTl[idx]=lo;
  }
  __syncthreads();
  #pragma unroll
  for (int yy=0; yy<32; yy+=8){
    float val = tile[x][y+yy]*inv;
    u16 hi, lo; hilo(val, hi, lo);
    long idx = zb + (long)(c0+y+yy)*256 + r0 + x;
    zNh[idx]=hi; zNl[idx]=lo;
  }
}

// ---------- Newton MFMA GEMM: 128x128 tile, split hi/lo bf16 (3-term), K=256 ----------
struct NCfg {
  const u16 *Ah, *Al, *Bh, *Bl;
  const u16 *E1h, *E1l, *E2h, *E2l;
  u16 *oH, *oL, *oBF;
  long strA, strB, strO;
  float sa, s1, s2;
  int Mvalid;
};

__launch_bounds__(256)
__global__ void k_nmm(NCfg c0, NCfg c1, NCfg c2){
  int gz = blockIdx.z;
  int bh = gz & 15, op = gz >> 4;
  NCfg C = (op==0) ? c0 : ((op==1) ? c1 : c2);
  __shared__ __align__(16) u16 AsH[128*32], AsL[128*32], BsH[128*32], BsL[128*32];
  int tid = threadIdx.x, wave = tid>>6, lane = tid&63;
  int m0 = blockIdx.x*128, n0 = blockIdx.y*128;
  int wr = wave>>1, wc = wave&1;
  f32x4 acc[4][4];
  #pragma unroll
  for (int i=0;i<4;i++)
    #pragma unroll
    for (int j=0;j<4;j++) acc[i][j] = (f32x4){0.f,0.f,0.f,0.f};

  const u16* Ah = C.Ah + (long)bh*C.strA;
  const u16* Al = C.Al + (long)bh*C.strA;
  const u16* Bh = C.Bh + (long)bh*C.strB;
  const u16* Bl = C.Bl + (long)bh*C.strB;

  int arow = wr*64 + (lane&15);
  int brow = wc*64 + (lane&15);
  int ach = (((lane>>4) ^ ((arow>>1)&3)))*8;
  int bch = (((lane>>4) ^ ((brow>>1)&3)))*8;

  for (int k0=0; k0<256; k0+=32){
    #pragma unroll
    for (int ci=0; ci<2; ++ci){
      int cc = wave*2 + ci;
      int r = (cc<<4) + (lane>>2), kq = lane&3;
      int kcs = k0 + ((kq ^ ((r>>1)&3))<<3);
      gload16(Ah + (long)(m0+r)*256 + kcs, &AsH[cc*512]);
      gload16(Al + (long)(m0+r)*256 + kcs, &AsL[cc*512]);
      gload16(Bh + (long)(n0+r)*256 + kcs, &BsH[cc*512]);
      gload16(Bl + (long)(n0+r)*256 + kcs, &BsL[cc*512]);
    }
    __syncthreads();
    short8 aH[4], aL[4], bH[4], bL[4];
    #pragma unroll
    for (int i=0;i<4;i++){
      aH[i] = *(const short8*)&AsH[(arow + i*16)*32 + ach];
      aL[i] = *(const short8*)&AsL[(arow + i*16)*32 + ach];
      bH[i] = *(const short8*)&BsH[(brow + i*16)*32 + bch];
      bL[i] = *(const short8*)&BsL[(brow + i*16)*32 + bch];
    }
    #pragma unroll
    for (int i=0;i<4;i++)
      #pragma unroll
      for (int j=0;j<4;j++){
        acc[i][j] = __builtin_amdgcn_mfma_f32_16x16x32_bf16(aH[i], bH[j], acc[i][j], 0,0,0);
        acc[i][j] = __builtin_amdgcn_mfma_f32_16x16x32_bf16(aH[i], bL[j], acc[i][j], 0,0,0);
        acc[i][j] = __builtin_amdgcn_mfma_f32_16x16x32_bf16(aL[i], bH[j], acc[i][j], 0,0,0);
      }
    __syncthreads();
  }

  int lr = lane>>4, lc = lane&15;
  long eb = (long)bh*65536;
  long ob = (long)bh*C.strO;
  #pragma unroll
  for (int j=0;j<4;j++){
    int cg = n0 + wc*64 + j*16 + lc;
    #pragma unroll
    for (int i=0;i<4;i++){
      #pragma unroll
      for (int r=0;r<4;r++){
        int rg = m0 + wr*64 + i*16 + lr*4 + r;
        if (rg >= C.Mvalid) continue;
        float val = C.sa*acc[i][j][r];
        long ei = eb + (long)rg*256 + cg;
        if (C.E1h) val += C.s1*(bf2f(C.E1h[ei]) + bf2f(C.E1l[ei]));
        if (C.E2h) val += C.s2*(bf2f(C.E2h[ei]) + bf2f(C.E2l[ei]));
        long oi = ob + (long)rg*256 + cg;
        if (C.oBF){
          C.oBF[oi] = f2bf(val);
        } else {
          u16 hi, lo; hilo(val, hi, lo);
          C.oH[oi]=hi; C.oL[oi]=lo;
        }
      }
    }
  }
}

// ---------- v -> vt bf16 transpose: vt[bh][64][8192] ----------
__launch_bounds__(256)
__global__ void k_vt(const float* v, u16* vt){
  __shared__ float tile[32][68];
  int pt = blockIdx.x, bh = blockIdx.y, t = threadIdx.x;
  int p = t>>3, d0 = (t&7)*8;
  const float* src = v + ((long)bh*8192 + pt*32 + p)*64 + d0;
  float4 a = *(const float4*)src;
  float4 b = *(const float4*)(src+4);
  tile[p][d0+0]=a.x; tile[p][d0+1]=a.y; tile[p][d0+2]=a.z; tile[p][d0+3]=a.w;
  tile[p][d0+4]=b.x; tile[p][d0+5]=b.y; tile[p][d0+6]=b.z; tile[p][d0+7]=b.w;
  __syncthreads();
  int pos2 = (t&15)*2;
  #pragma unroll
  for (int ll=0; ll<4; ++ll){
    int d = (t>>4) + 16*ll;
    unsigned val = pk2(tile[pos2][d], tile[pos2+1][d]);
    *(unsigned*)&vt[((long)(bh*64 + d))*8192 + pt*32 + pos2] = val;
  }
}

// ---------- MFMA flash ----------
template<int OM>
__launch_bounds__(256)
__global__ void k_flash2(const float* Q, const float* K, const u16* VT,
                         float* op, float* ml, u16* hb,
                         int kvchunk, long qbh, long kbh, long vtbh, int vtrow){
  __shared__ __align__(16) u16 KT[64*64];
  __shared__ __align__(16) u16 VTs[64*64];
  __shared__ __align__(16) u16 Pb[4*16*72];
  int bh = blockIdx.y, qt = blockIdx.x, sk = (OM==0) ? blockIdx.z : 0;
  int t = threadIdx.x, w = t>>6, l = t&63;
  int lq = l&15, hi = l>>4;

  short8 qf[2];
  {
    const float* qp = Q + (long)bh*qbh + (long)(qt*64 + w*16 + lq)*64 + hi*8;
    #pragma unroll
    for (int kh=0; kh<2; ++kh){
      float4 f0 = *(const float4*)(qp + kh*32);
      float4 f1 = *(const float4*)(qp + kh*32 + 4);
      union { short8 s; uint4 u; } c;
      c.u.x = pk2(f0.x,f0.y); c.u.y = pk2(f0.z,f0.w);
      c.u.z = pk2(f1.x,f1.y); c.u.w = pk2(f1.z,f1.w);
      qf[kh] = c.s;
    }
  }
  float m_run = -1e30f, l_run = 0.f;
  f32x4 o[4];
  #pragma unroll
  for (int i=0;i<4;i++) o[i] = (f32x4){0.f,0.f,0.f,0.f};

  const float* kbase = K + (long)bh*kbh;
  const u16* vtbase = VT + (long)bh*vtbh;
  char* Pw = (char*)&Pb[w*16*72];
  int kv0 = sk*kvchunk;

  for (int p0 = kv0; p0 < kv0 + kvchunk; p0 += 64){
    {
      int r = w*16 + (l>>2), d0 = (l&3)*16;
      const float* kr = kbase + (long)(p0 + r)*64 + d0;
      float4 f0 = *(const float4*)(kr+0);
      float4 f1 = *(const float4*)(kr+4);
      float4 f2 = *(const float4*)(kr+8);
      float4 f3 = *(const float4*)(kr+12);
      float fv[16] = {f0.x,f0.y,f0.z,f0.w,f1.x,f1.y,f1.z,f1.w,
                      f2.x,f2.y,f2.z,f2.w,f3.x,f3.y,f3.z,f3.w};
      #pragma unroll
      for (int m=0;m<8;m++){
        int d = d0 + 2*m;
        int byte = (r*128 + d*2) ^ ((r&7)<<4);
        *(unsigned*)((char*)KT + byte) = pk2(fv[2*m], fv[2*m+1]);
      }
    }
    #pragma unroll
    for (int ii=0; ii<2; ++ii){
      int inst = w*2 + ii;
      int d = inst*8 + (l>>3);
      int srcoff = ((l&7)*16) ^ ((d&7)<<4);
      const char* src = (const char*)(vtbase + (long)d*vtrow + p0) + srcoff;
      gload16(src, (char*)VTs + inst*1024);
    }
    __syncthreads();
    f32x4 s[4];
    #pragma unroll
    for (int i=0;i<4;i++){
      s[i] = (f32x4){0.f,0.f,0.f,0.f};
      #pragma unroll
      for (int kh=0;kh<2;kh++){
        int kvr = i*16 + lq;
        int byte = (kvr*128 + hi*16 + kh*64) ^ ((kvr&7)<<4);
        short8 kf = *(const short8*)((const char*)KT + byte);
        s[i] = __builtin_amdgcn_mfma_f32_16x16x32_bf16(kf, qf[kh], s[i], 0,0,0);
      }
    }
    float tm = -1e30f;
    #pragma unroll
    for (int i=0;i<4;i++)
      #pragma unroll
      for (int r=0;r<4;r++) tm = fmaxf(tm, s[i][r]);
    tm = fmaxf(tm, __shfl_xor(tm, 16));
    tm = fmaxf(tm, __shfl_xor(tm, 32));
    float mnew = fmaxf(m_run, tm);
    float scale = __expf(m_run - mnew);
    float tsum = 0.f;
    #pragma unroll
    for (int i=0;i<4;i++)
      #pragma unroll
      for (int r=0;r<4;r++){ float e = __expf(s[i][r]-mnew); s[i][r]=e; tsum += e; }
    tsum += __shfl_xor(tsum, 16);
    tsum += __shfl_xor(tsum, 32);
    l_run = l_run*scale + tsum;
    m_run = mnew;
    #pragma unroll
    for (int i=0;i<4;i++)
      #pragma unroll
      for (int r=0;r<4;r++) o[i][r] *= scale;
    #pragma unroll
    for (int i=0;i<4;i++){
      int byte = lq*144 + (i*16 + hi*4)*2;
      *(unsigned*)(Pw + byte)     = pk2(s[i][0], s[i][1]);
      *(unsigned*)(Pw + byte + 4) = pk2(s[i][2], s[i][3]);
    }
    short8 pf[2];
    #pragma unroll
    for (int kh=0;kh<2;kh++)
      pf[kh] = *(const short8*)(Pw + lq*144 + hi*16 + kh*64);
    #pragma unroll
    for (int i=0;i<4;i++){
      #pragma unroll
      for (int kh=0;kh<2;kh++){
        int d = i*16 + lq;
        int byte = (d*128 + hi*16 + kh*64) ^ ((d&7)<<4);
        short8 vf = *(const short8*)((const char*)VTs + byte);
        o[i] = __builtin_amdgcn_mfma_f32_16x16x32_bf16(vf, pf[kh], o[i], 0,0,0);
      }
    }
    __syncthreads();
  }

  int qrow = qt*64 + w*16 + lq;
  if constexpr (OM == 0){
    long ob = ((long)(sk*16+bh)*256 + qrow)*64;
    #pragma unroll
    for (int i=0;i<4;i++)
      #pragma unroll
      for (int r=0;r<4;r++) op[ob + i*16 + hi*4 + r] = o[i][r];
    if (l < 16){
      long mi = ((long)(sk*16+bh)*256 + qt*64 + w*16 + l)*2;
      ml[mi] = m_run; ml[mi+1] = l_run;
    }
  } else {
    float invl = 1.f/l_run;
    long hb0 = ((long)bh*8192 + qrow)*64;
    #pragma unroll
    for (int i=0;i<4;i++)
      #pragma unroll
      for (int r=0;r<4;r++){
        long idx = hb0 + i*16 + hi*4 + r;
        hb[idx] = f2bf(bf2f(hb[idx]) + o[i][r]*invl);
      }
  }
}

// ---------- combine split-K flash partials (16 chunks) -> w3T hi/lo planes ----------
__global__ void k_fcomb(const float* op, const float* ml, u16* w3Th, u16* w3Tl){
  int bh = blockIdx.y, rt = blockIdx.x, t = threadIdx.x;
  int row = rt*16 + (t>>4), d0 = (t&15)*4;
  float M = -1e30f;
  for (int s=0;s<16;s++) M = fmaxf(M, ml[(((long)(s*16+bh)*256)+row)*2]);
  float lt = 0.f;
  float4 o = {0,0,0,0};
  for (int s=0;s<16;s++){
    long base = ((long)(s*16+bh)*256)+row;
    float w = __expf(ml[base*2]-M);
    lt += ml[base*2+1]*w;
    float4 ov = *(const float4*)&op[base*64 + d0];
    o.x += ov.x*w; o.y += ov.y*w; o.z += ov.z*w; o.w += ov.w*w;
  }
  float inv = 1.f/lt;
  float vals[4] = {o.x*inv, o.y*inv, o.z*inv, o.w*inv};
  #pragma unroll
  for (int dd=0; dd<4; ++dd){
    u16 hi, lo; hilo(vals[dd], hi, lo);
    long idx = (long)bh*32768 + (long)(d0+dd)*256 + row;
    w3Th[idx]=hi; w3Tl[idx]=lo;
  }
}

// ---------- depthwise conv residual -> headsb (init write) ----------
__launch_bounds__(256)
__global__ void k_conv(const float* v, const float* cw, u16* heads){
  __shared__ float vsl[160][64];
  __shared__ float cws[33];
  int bh = blockIdx.y, pt = blockIdx.x, t = threadIdx.x;
  int hh = bh & 7;
  if (t < 33) cws[t] = cw[hh*33 + t];
  int p0 = pt*128;
  const float* vp = v + (long)bh*8192*64;
  for (int l=0;l<10;l++){
    int fidx = (l*256 + t)*4;
    int r = fidx>>6, c = fidx&63;
    int gp = p0 - 16 + r;
    if (gp>=0 && gp<8192){
      float4 a = *(const float4*)(vp + (long)gp*64 + c);
      vsl[r][c]=a.x; vsl[r][c+1]=a.y; vsl[r][c+2]=a.z; vsl[r][c+3]=a.w;
    } else {
      vsl[r][c]=0.f; vsl[r][c+1]=0.f; vsl[r][c+2]=0.f; vsl[r][c+3]=0.f;
    }
  }
  __syncthreads();
  int d = t & 63, pg = t >> 6;
  u16* hp = heads + ((long)bh*8192 + p0)*64;
  for (int pp=0; pp<32; pp++){
    int pl = pp*4 + pg;
    float acc = 0.f;
    #pragma unroll
    for (int tt=0; tt<33; tt++) acc += vsl[pl+tt][d]*cws[tt];
    hp[(long)pl*64 + d] = f2bf(acc);
  }
}

// ---------- final ----------
__global__ void k_final(const float* hbuf, const float* g, const float* bt,
                        const float* fw, const float* fb, float* outp){
  int b = blockIdx.x, t = threadIdx.x;
  __shared__ float red[4];
  __shared__ float sx[512];
  __shared__ float lg[4];
  const float* x = hbuf + ((long)b*8192+191)*512;
  float2 xv = *(const float2*)(x + t*2);
  float s = xv.x + xv.y;
  for (int off=32; off; off>>=1) s += __shfl_down(s,off,64);
  if ((t&63)==0) red[t>>6]=s;
  __syncthreads();
  float mean = (red[0]+red[1]+red[2]+red[3])*(1.f/512.f);
  __syncthreads();
  float d0 = xv.x-mean, d1 = xv.y-mean;
  float ssq = d0*d0 + d1*d1;
  for (int off=32; off; off>>=1) ssq += __shfl_down(ssq,off,64);
  if ((t&63)==0) red[t>>6]=ssq;
  __syncthreads();
  float rstd = rsqrtf((red[0]+red[1]+red[2]+red[3])*(1.f/512.f) + 1e-5f);
  sx[t*2]   = d0*rstd*g[t*2]   + bt[t*2];
  sx[t*2+1] = d1*rstd*g[t*2+1] + bt[t*2+1];
  __syncthreads();
  int c = t>>7, jj = t&127;
  float part = 0.f;
  for (int kk=jj; kk<512; kk+=128) part += sx[kk]*fw[(long)kk*2 + c];
  for (int off=1; off<64; off<<=1) part += __shfl_xor(part,off,64);
  if ((t&63)==0) lg[t>>6]=part;
  __syncthreads();
  if (t==0){
    float l0 = lg[0]+lg[1] + fb[0];
    float l1 = lg[2]+lg[3] + fb[1];
    float m = fmaxf(l0,l1);
    float e0 = __expf(l0-m), e1 = __expf(l1-m);
    float inv = 1.f/(e0+e1);
    outp[b*2+0]=l0; outp[b*2+1]=l1;
    outp[4+b*2+0]=e0*inv; outp[4+b*2+1]=e1*inv;
    outp[8+b]=(l1>l0) ? 1.f : 0.f;
  }
}

// ===================== host launch =====================
static NCfg mkcfg(const u16* Ah,const u16* Al,const u16* Bh,const u16* Bl,
                  const u16* E1h,const u16* E1l,const u16* E2h,const u16* E2l,
                  u16* oH,u16* oL,u16* oBF,long strA,long strB,long strO,
                  float sa,float s1,float s2,int Mv){
  NCfg c; c.Ah=Ah;c.Al=Al;c.Bh=Bh;c.Bl=Bl;c.E1h=E1h;c.E1l=E1l;c.E2h=E2h;c.E2l=E2l;
  c.oH=oH;c.oL=oL;c.oBF=oBF;c.strA=strA;c.strB=strB;c.strO=strO;
  c.sa=sa;c.s1=s1;c.s2=s2;c.Mvalid=Mv; return c;
}

extern "C" void kernel_launch(void* const* d_in, const int* in_sizes, int n_in,
                              void* d_out, int out_size, void* d_ws, size_t ws_size,
                              hipStream_t stream){
  (void)in_sizes; (void)n_in; (void)out_size; (void)ws_size;
  const long TOK = (long)2*8192*512;       // 8,388,608
  const long PL = 1048576;                 // plane: 16*256*256 u16
  float* W    = (float*)d_ws;
  float* rc   = W;                          // 64
  float* h    = W + 64;
  float* q    = h + TOK;
  float* k    = q + TOK;
  float* v    = k + TOK;
  u16*  xlnb  = (u16*)(v + TOK);            // TOK u16; z-planes alias (disjoint lifetime)
  u16*  zPl   = xlnb;                       // 8 planes exactly = TOK u16
  u16*  headsb= xlnb + TOK;
  u16*  wT    = headsb + TOK;               // 1,048,576 u16
  float* ql   = (float*)(wT + PL);
  float* kl   = ql + 262144;
  float* a2f  = kl + 262144;                // 1,048,576 f32 (ml alias after z0p)
  u16*  a2Nh  = (u16*)(a2f + 1048576);
  u16*  a2Nl  = a2Nh + PL;
  u16*  YNh   = a2Nl + PL;
  u16*  YNl   = YNh + PL;
  u16*  YTh   = YNl + PL;
  u16*  YTl   = YTh + PL;
  u16*  Gth   = YTl + PL;
  u16*  Gtl   = Gth + PL;
  u16*  PNh   = Gtl + PL;
  u16*  PNl   = PNh + PL;
  u16*  PTh   = PNl + PL;
  u16*  PTl   = PTh + PL;
  u16*  w3Th  = PTl + PL;                   // 16*128*256 = 524288 u16 (rows 64..127 pad)
  u16*  w3Tl  = w3Th + 524288;
  u16*  zwT   = w3Tl + 524288;              // 16*64*256
  u16*  vt    = zwT + 262144;               // TOK u16
  float* op   = v;                          // a3 partials alias v (dead after vt/conv)
  float* ml   = a2f;                        // alias, a2f dead after z0p

  // z plane sets (alias xlnb region)
  u16* zN_h[2] = { zPl,        zPl + 4*PL };
  u16* zN_l[2] = { zPl + PL,   zPl + 5*PL };
  u16* zT_h[2] = { zPl + 2*PL, zPl + 6*PL };
  u16* zT_l[2] = { zPl + 3*PL, zPl + 7*PL };

  dim3 B(256);

  k_cls<<<dim3(2), B, 0, stream>>>((const float*)d_in[3], h);
  k_cvtT<<<dim3(16,32), B, 0, stream>>>((const float*)d_in[1], wT, 1024, 512);
  k_gemm<0><<<dim3(4,125), B, 0, stream>>>(d_in[0], wT, (const float*)d_in[2],
                                           h, nullptr,nullptr,nullptr, 16000,512,1024);

  for (int blk=0; blk<2; ++blk){
    const float* lng  = (const float*)d_in[blk?10:4];
    const float* lnb  = (const float*)d_in[blk?11:5];
    const float* qkvw = (const float*)d_in[blk?12:6];
    const float* outw = (const float*)d_in[blk?13:7];
    const float* outb = (const float*)d_in[blk?14:8];
    const float* cw   = (const float*)d_in[blk?15:9];

    k_ln<<<dim3(16384), B, 0, stream>>>(h, lng, lnb, xlnb);

    k_cvtT<<<dim3(48,16), B, 0, stream>>>(qkvw, wT, 512, 1536);
    k_gemm<1><<<dim3(12,128), B, 0, stream>>>(xlnb, wT, nullptr,
                                              nullptr, q,k,v, 16384,1536,512);

    k_landmark<<<dim3(256,16), dim3(64), 0, stream>>>(q, ql);
    k_landmark<<<dim3(256,16), dim3(64), 0, stream>>>(k, kl);

    k_vt<<<dim3(256,16), B, 0, stream>>>(v, vt);
    k_conv<<<dim3(64,16), B, 0, stream>>>(v, cw, headsb);

    k_a2<<<dim3(16,16), B, 0, stream>>>(ql, kl, a2f, a2Nh, a2Nl);
    k_colrow<<<dim3(16), B, 0, stream>>>(a2f, rc);
    k_denom<<<dim3(1), dim3(1), 0, stream>>>(rc, rc+32);
    k_z0p<<<dim3(8,8,16), B, 0, stream>>>(a2f, rc+32, zN_h[0],zN_l[0],zT_h[0],zT_l[0]);

    NCfg nil = mkcfg(nullptr,nullptr,nullptr,nullptr,nullptr,nullptr,nullptr,nullptr,
                     nullptr,nullptr,nullptr,0,0,0,0,0,0,0);
    for (int it=0; it<6; ++it){
      int zi = it&1, zo = (it+1)&1;
      // S1: Y = a2@z ; Y^T = z^T@a2^T
      NCfg s1a = mkcfg(a2Nh,a2Nl, zT_h[zi],zT_l[zi], nullptr,nullptr,nullptr,nullptr,
                       YNh,YNl,nullptr, 65536,65536,65536, 1.f,0.f,0.f, 256);
      NCfg s1b = mkcfg(zT_h[zi],zT_l[zi], a2Nh,a2Nl, nullptr,nullptr,nullptr,nullptr,
                       YTh,YTl,nullptr, 65536,65536,65536, 1.f,0.f,0.f, 256);
      k_nmm<<<dim3(2,2,32), B, 0, stream>>>(s1a, s1b, nil);
      // S2: G^T = 7Y^T - Y^T@Y^T ; P = z@Y ; P^T = Y^T@z^T
      NCfg s2a = mkcfg(YTh,YTl, YNh,YNl, YTh,YTl,nullptr,nullptr,
                       Gth,Gtl,nullptr, 65536,65536,65536, -1.f,7.f,0.f, 256);
      NCfg s2b = mkcfg(zN_h[zi],zN_l[zi], YTh,YTl, nullptr,nullptr,nullptr,nullptr,
                       PNh,PNl,nullptr, 65536,65536,65536, 1.f,0.f,0.f, 256);
      NCfg s2c = mkcfg(YTh,YTl, zT_h[zi],zT_l[zi], nullptr,nullptr,nullptr,nullptr,
                       PTh,PTl,nullptr, 65536,65536,65536, 1.f,0.f,0.f, 256);
      k_nmm<<<dim3(2,2,48), B, 0, stream>>>(s2a, s2b, s2c);
      // S3: z' = 0.25 P@G + 3.25 z - 3.75 P ; z'^T = 0.25 G^T@P^T + 3.25 z^T - 3.75 P^T
      NCfg s3a = mkcfg(PNh,PNl, Gth,Gtl, zN_h[zi],zN_l[zi], PNh,PNl,
                       zN_h[zo],zN_l[zo],nullptr, 65536,65536,65536, 0.25f,3.25f,-3.75f, 256);
      NCfg s3b = mkcfg(Gth,Gtl, PNh,PNl, zT_h[zi],zT_l[zi], PTh,PTl,
                       zT_h[zo],zT_l[zo],nullptr, 65536,65536,65536, 0.25f,3.25f,-3.75f, 256);
      k_nmm<<<dim3(2,2,32), B, 0, stream>>>(s3a, s3b, nil);
    }

    // a3: w3 = softmax(q_l @ k^T) @ v  (split-K 16 chunks of 512) -> w3T planes
    k_flash2<0><<<dim3(4,16,16), B, 0, stream>>>(ql, k, vt, op, ml, nullptr,
                                                 512, 16384L, 524288L, 524288L, 8192);
    k_fcomb<<<dim3(16,16), B, 0, stream>>>(op, ml, w3Th, w3Tl);
    // zw^T bf16 = w3^T @ z^T   (z final in set 0)
    NCfg zwc = mkcfg(w3Th,w3Tl, zN_h[0],zN_l[0], nullptr,nullptr,nullptr,nullptr,
                     nullptr,nullptr,zwT, 32768,65536,16384, 1.f,0.f,0.f, 64);
    NCfg nil2 = zwc;
    k_nmm<<<dim3(1,2,16), B, 0, stream>>>(zwc, nil2, nil2);
    // a1: headsb += softmax(q @ k_l^T) @ zw
    k_flash2<1><<<dim3(128,16,1), B, 0, stream>>>(q, kl, zwT, nullptr, nullptr, headsb,
                                                  256, 524288L, 16384L, 16384L, 256);

    k_cvtT<<<dim3(16,16), B, 0, stream>>>(outw, wT, 512, 512);
    k_gemm<2><<<dim3(4,128), B, 0, stream>>>(headsb, wT, outb,
                                             h, nullptr,nullptr,nullptr, 16384,512,512);
  }

  k_final<<<dim3(2), B, 0, stream>>>(h, (const float*)d_in[16], (const float*)d_in[17],
                                     (const float*)d_in[18], (const float*)d_in[19], (float*)d_out);
}

// Round 5
// 1202.243 us; speedup vs baseline: 1.5342x; 1.5342x over previous
//
#include <hip/hip_runtime.h>

typedef unsigned short u16;
typedef __attribute__((ext_vector_type(8))) short short8;
typedef __attribute__((ext_vector_type(4))) float f32x4;

__device__ __forceinline__ float bf2f(u16 x){
  union { unsigned u; float f; } c; c.u = ((unsigned)x) << 16; return c.f;
}
__device__ __forceinline__ u16 f2bf(float f){
  union { float f; unsigned u; } c; c.f = f;
  unsigned u = c.u;
  return (u16)((u + 0x7FFFu + ((u >> 16) & 1u)) >> 16);
}
__device__ __forceinline__ unsigned pk2(float a, float b){
  return (unsigned)f2bf(a) | ((unsigned)f2bf(b) << 16);
}
__device__ __forceinline__ void hilo(float v, u16& hi, u16& lo){
  hi = f2bf(v); lo = f2bf(v - bf2f(hi));
}

__device__ __forceinline__ void gload16(const void* g, void* l){
  __builtin_amdgcn_global_load_lds(
    (const __attribute__((address_space(1))) void*)g,
    (__attribute__((address_space(3))) void*)l, 16, 0, 0);
}

// ---------- cls token ----------
__global__ void k_cls(const float* cls, float* h){
  int b = blockIdx.x, t = threadIdx.x;
  for (int c=t; c<512; c+=256)
    h[((long)b*8192+191)*512 + c] = cls[c];
}

// ---------- weight convert + transpose: W f32 [K][N] -> wT bf16 [N][K] ----------
__global__ void k_cvtT(const float* Wm, u16* wT, int K, int N){
  __shared__ float tile[32][33];
  int n0 = blockIdx.x*32, k0 = blockIdx.y*32;
  int x = threadIdx.x & 31, y = threadIdx.x >> 5;
  #pragma unroll
  for (int p=0;p<4;p++) tile[y+8*p][x] = Wm[(long)(k0+y+8*p)*N + n0 + x];
  __syncthreads();
  #pragma unroll
  for (int p=0;p<4;p++) wT[(long)(n0+y+8*p)*K + k0 + x] = f2bf(tile[x][y+8*p]);
}

// ---------- MFMA GEMM: 128x128 tile, BK=32, 4 waves, transposed epilogue ----------
// acc[i][j] = mfma(bf[j], af[i]) -> lane holds: token = lane&15, 4 consecutive channels.
template<int MODE>
__launch_bounds__(256)
__global__ void k_gemm(const void* Av, const u16* Bt, const float* bias,
                       float* hout, float* qo, float* ko, float* vo,
                       int M, int N, int K){
  __shared__ __align__(16) u16 As[128*32];
  __shared__ __align__(16) u16 Bs[128*32];
  const int tid = threadIdx.x;
  const int wave = tid>>6, lane = tid&63;
  const int m0 = blockIdx.x*128, n0 = blockIdx.y*128;
  const int wr = wave>>1, wc = wave&1;
  f32x4 acc[4][4];
  #pragma unroll
  for (int i=0;i<4;i++)
    #pragma unroll
    for (int j=0;j<4;j++) acc[i][j] = (f32x4){0.f,0.f,0.f,0.f};

  for (int k0=0; k0<K; k0+=32){
    if constexpr (MODE == 0){
      int r = tid>>1, half = tid&1;
      const float* gp = (const float*)Av + (long)(m0+r)*K + k0 + half*16;
      float4 f0 = *(const float4*)(gp+0);
      float4 f1 = *(const float4*)(gp+4);
      float4 f2 = *(const float4*)(gp+8);
      float4 f3 = *(const float4*)(gp+12);
      uint4 pa, pb;
      pa.x = pk2(f0.x,f0.y); pa.y = pk2(f0.z,f0.w);
      pa.z = pk2(f1.x,f1.y); pa.w = pk2(f1.z,f1.w);
      pb.x = pk2(f2.x,f2.y); pb.y = pk2(f2.z,f2.w);
      pb.z = pk2(f3.x,f3.y); pb.w = pk2(f3.z,f3.w);
      uint4* dst = (uint4*)&As[r*32 + half*16];
      dst[0] = pa; dst[1] = pb;
    } else {
      #pragma unroll
      for (int ci=0; ci<2; ++ci){
        int c = wave*2 + ci;
        int r = (c<<4) + (lane>>2), kq = lane&3;
        const u16* gp;
        if constexpr (MODE == 1){
          gp = (const u16*)Av + (long)(m0+r)*K + k0 + kq*8;
        } else {
          int rr = m0 + r; int b = rr>>13, pos = rr&8191;
          int cc = k0 + kq*8; int hh = cc>>6, d = cc&63;
          gp = (const u16*)Av + ((long)(b*8+hh)*8192 + pos)*64 + d;
        }
        gload16(gp, &As[c*512]);
      }
    }
    #pragma unroll
    for (int ci=0; ci<2; ++ci){
      int c = wave*2 + ci;
      int r = (c<<4) + (lane>>2), kq = lane&3;
      gload16(Bt + (long)(n0+r)*K + k0 + kq*8, &Bs[c*512]);
    }
    __syncthreads();
    short8 af[4], bf[4];
    int arow = wr*64 + (lane&15);
    int brow = wc*64 + (lane&15);
    int koff = (lane>>4)*8;
    #pragma unroll
    for (int i=0;i<4;i++){
      af[i] = *(const short8*)&As[(arow + i*16)*32 + koff];
      bf[i] = *(const short8*)&Bs[(brow + i*16)*32 + koff];
    }
    #pragma unroll
    for (int i=0;i<4;i++)
      #pragma unroll
      for (int j=0;j<4;j++)
        acc[i][j] = __builtin_amdgcn_mfma_f32_16x16x32_bf16(bf[j], af[i], acc[i][j], 0,0,0);
    __syncthreads();
  }

  const int lc = lane&15, hi4 = (lane>>4)*4;
  if constexpr (MODE == 0){
    #pragma unroll
    for (int j=0;j<4;j++){
      int cb = n0 + wc*64 + j*16 + hi4;
      float4 bb = *(const float4*)&bias[cb];
      #pragma unroll
      for (int i=0;i<4;i++){
        int row = m0 + wr*64 + i*16 + lc;
        int b = (row >= 8000) ? 1 : 0;
        int tok = row - b*8000;
        float4 o;
        o.x = fmaxf(acc[i][j][0] + bb.x, 0.f);
        o.y = fmaxf(acc[i][j][1] + bb.y, 0.f);
        o.z = fmaxf(acc[i][j][2] + bb.z, 0.f);
        o.w = fmaxf(acc[i][j][3] + bb.w, 0.f);
        *(float4*)&hout[((long)(b*8192 + 192 + tok))*512 + cb] = o;
      }
    }
  } else if constexpr (MODE == 1){
    #pragma unroll
    for (int j=0;j<4;j++){
      int cb = n0 + wc*64 + j*16 + hi4;
      int which = cb>>9, head = (cb>>6)&7, d = cb&63;
      float* base = (which==0) ? qo : (which==1 ? ko : vo);
      float scale = (which==0) ? 0.125f : 1.0f;
      #pragma unroll
      for (int i=0;i<4;i++){
        int row = m0 + wr*64 + i*16 + lc;
        int b = row>>13, pos = row&8191;
        float4 o;
        o.x = acc[i][j][0]*scale; o.y = acc[i][j][1]*scale;
        o.z = acc[i][j][2]*scale; o.w = acc[i][j][3]*scale;
        *(float4*)&base[((long)(b*8+head)*8192 + pos)*64 + d] = o;
      }
    }
  } else {
    #pragma unroll
    for (int j=0;j<4;j++){
      int cb = n0 + wc*64 + j*16 + hi4;
      float4 bb = *(const float4*)&bias[cb];
      #pragma unroll
      for (int i=0;i<4;i++){
        int row = m0 + wr*64 + i*16 + lc;
        int pos = row&8191;
        if (pos < 191) continue;
        float4* p = (float4*)&hout[(long)row*512 + cb];
        float4 cur = *p;
        cur.x += acc[i][j][0] + bb.x;
        cur.y += acc[i][j][1] + bb.y;
        cur.z += acc[i][j][2] + bb.z;
        cur.w += acc[i][j][3] + bb.w;
        *p = cur;
      }
    }
  }
}

// ---------- layernorm: h f32 -> xln bf16 (pad rows -> 0) ----------
__global__ void k_ln(const float* hsrc, const float* g, const float* bt, u16* xlnb){
  int row = blockIdx.x;
  int pos = row & 8191;
  int t = threadIdx.x;
  long base = (long)row*512 + t*2;
  if (pos < 191){ *(unsigned*)&xlnb[base] = 0u; return; }
  float2 x = *(const float2*)(hsrc + base);
  __shared__ float red[4];
  float s = x.x + x.y;
  for (int off=32; off; off>>=1) s += __shfl_down(s, off, 64);
  if ((t&63)==0) red[t>>6]=s;
  __syncthreads();
  float mean = (red[0]+red[1]+red[2]+red[3]) * (1.f/512.f);
  __syncthreads();
  float d0 = x.x-mean, d1 = x.y-mean;
  float ss = d0*d0 + d1*d1;
  for (int off=32; off; off>>=1) ss += __shfl_down(ss, off, 64);
  if ((t&63)==0) red[t>>6]=ss;
  __syncthreads();
  float rstd = rsqrtf((red[0]+red[1]+red[2]+red[3])*(1.f/512.f) + 1e-5f);
  float o0 = d0*rstd*g[t*2]   + bt[t*2];
  float o1 = d1*rstd*g[t*2+1] + bt[t*2+1];
  *(unsigned*)&xlnb[base] = pk2(o0, o1);
}

// ---------- landmark means ----------
__global__ void k_landmark(const float* src, float* dst){
  int g = blockIdx.x, bh = blockIdx.y, d = threadIdx.x;
  const float* p = src + (((long)bh*8192) + g*32)*64 + d;
  float s = 0.f;
  #pragma unroll
  for (int j=0;j<32;j++) s += p[j*64];
  dst[((long)bh*256 + g)*64 + d] = s*(1.f/32.f);
}

// ---------- a2 = softmax(q_l @ k_l^T): f32 + hi/lo N-planes ----------
__launch_bounds__(256)
__global__ void k_a2(const float* qlm, const float* klm, float* a2, u16* a2Nh, u16* a2Nl){
  __shared__ float qls[16][68];
  __shared__ float kls[64][65];
  __shared__ float Sf[16][260];
  __shared__ float red[4];
  int bh = blockIdx.y, rt = blockIdx.x, t = threadIdx.x;
  const float* qp = qlm + ((long)bh*256 + rt*16)*64;
  { int fidx = t*4; int r = fidx>>6, c = fidx&63;
    float4 a = *(const float4*)(qp + fidx);
    qls[r][c]=a.x; qls[r][c+1]=a.y; qls[r][c+2]=a.z; qls[r][c+3]=a.w; }
  const float* kp = klm + (long)bh*16384;
  int cl = t & 63, ig = t >> 6;
  for (int kt=0; kt<4; ++kt){
    __syncthreads();
    for (int l=0;l<4;l++){
      int fidx = (l*256+t)*4; int r = fidx>>6, c = fidx&63;
      float4 a = *(const float4*)(kp + (long)(kt*64+r)*64 + c);
      kls[r][c]=a.x; kls[r][c+1]=a.y; kls[r][c+2]=a.z; kls[r][c+3]=a.w;
    }
    __syncthreads();
    float s0=0,s1=0,s2=0,s3=0;
    #pragma unroll
    for (int d=0;d<64;d++){
      float kv = kls[cl][d];
      s0 += qls[ig*4+0][d]*kv;
      s1 += qls[ig*4+1][d]*kv;
      s2 += qls[ig*4+2][d]*kv;
      s3 += qls[ig*4+3][d]*kv;
    }
    Sf[ig*4+0][kt*64+cl]=s0;
    Sf[ig*4+1][kt*64+cl]=s1;
    Sf[ig*4+2][kt*64+cl]=s2;
    Sf[ig*4+3][kt*64+cl]=s3;
  }
  __syncthreads();
  long ab = ((long)bh*256 + rt*16)*256;
  for (int i=0;i<16;i++){
    float val = Sf[i][t];
    float m = val;
    for (int off=1; off<64; off<<=1) m = fmaxf(m, __shfl_xor(m,off,64));
    if ((t&63)==0) red[t>>6]=m;
    __syncthreads();
    m = fmaxf(fmaxf(red[0],red[1]),fmaxf(red[2],red[3]));
    __syncthreads();
    float e = __expf(val - m);
    float sum = e;
    for (int off=1; off<64; off<<=1) sum += __shfl_xor(sum,off,64);
    if ((t&63)==0) red[t>>6]=sum;
    __syncthreads();
    sum = red[0]+red[1]+red[2]+red[3];
    __syncthreads();
    float o = e/sum;
    long idx = ab + (long)i*256 + t;
    a2[idx] = o;
    u16 hi, lo; hilo(o, hi, lo);
    a2Nh[idx]=hi; a2Nl[idx]=lo;
  }
}

// ---------- pinv denominator ----------
__global__ void k_colrow(const float* a2, float* rc){
  int bh = blockIdx.x, t = threadIdx.x;
  const float* p = a2 + (long)bh*65536;
  float cs=0.f, rs=0.f;
  for (int r=0;r<256;r++) cs += fabsf(p[(long)r*256 + t]);
  for (int c=0;c<256;c++) rs += fabsf(p[(long)t*256 + c]);
  __shared__ float red[4];
  for (int off=32; off; off>>=1) cs = fmaxf(cs, __shfl_down(cs,off,64));
  if ((t&63)==0) red[t>>6]=cs;
  __syncthreads();
  if (t==0) rc[bh] = fmaxf(fmaxf(red[0],red[1]),fmaxf(red[2],red[3]));
  __syncthreads();
  for (int off=32; off; off>>=1) rs = fmaxf(rs, __shfl_down(rs,off,64));
  if ((t&63)==0) red[t>>6]=rs;
  __syncthreads();
  if (t==0) rc[16+bh] = fmaxf(fmaxf(red[0],red[1]),fmaxf(red[2],red[3]));
}
__global__ void k_denom(const float* rc, float* denom){
  float cm=0.f, rm=0.f;
  for (int i=0;i<16;i++){ cm=fmaxf(cm,rc[i]); rm=fmaxf(rm,rc[16+i]); }
  *denom = cm*rm;
}

// ---------- z0 planes ----------
__global__ void k_z0p(const float* a2, const float* denom,
                      u16* zNh, u16* zNl, u16* zTh, u16* zTl){
  __shared__ float tile[32][33];
  int bh = blockIdx.z;
  int c0 = blockIdx.x*32, r0 = blockIdx.y*32;
  int x = threadIdx.x & 31, y = threadIdx.x >> 5;
  const float* p = a2 + (long)bh*65536;
  float inv = 1.0f / (*denom);
  long zb = (long)bh*65536;
  #pragma unroll
  for (int yy=0; yy<32; yy+=8){
    float vv = p[(long)(r0+y+yy)*256 + c0 + x];
    tile[y+yy][x] = vv;
    float val = vv*inv;
    u16 hi, lo; hilo(val, hi, lo);
    long idx = zb + (long)(r0+y+yy)*256 + c0 + x;
    zTh[idx]=hi; zTl[idx]=lo;
  }
  __syncthreads();
  #pragma unroll
  for (int yy=0; yy<32; yy+=8){
    float val = tile[x][y+yy]*inv;
    u16 hi, lo; hilo(val, hi, lo);
    long idx = zb + (long)(c0+y+yy)*256 + r0 + x;
    zNh[idx]=hi; zNl[idx]=lo;
  }
}

// ---------- Newton MFMA GEMM v2: 64x64 tiles, C = A@B^T, dual-orientation epilogue ----------
struct NC {
  const u16 *Ah, *Al, *Bh, *Bl;
  const u16 *E1h, *E1l, *E2h, *E2l;
  u16 *oNh, *oNl, *oTh, *oTl, *oBF;
  long strA, strB, strO;
  float sa, s1, s2;
};

__launch_bounds__(256)
__global__ void k_nmm(NC c0, NC c1){
  int gz = blockIdx.z;
  int bh = gz & 15;
  NC C = (gz>>4) ? c1 : c0;
  __shared__ __align__(16) char smem[64*68*4];   // staging 16KB | T 64x68 f32
  u16* AsH = (u16*)smem;
  u16* AsL = (u16*)(smem + 4096);
  u16* BsH = (u16*)(smem + 8192);
  u16* BsL = (u16*)(smem + 12288);
  float* T = (float*)smem;
  int tid = threadIdx.x, wave = tid>>6, lane = tid&63;
  int m0 = blockIdx.x*64, n0 = blockIdx.y*64;
  int wr = wave>>1, wc = wave&1;
  int lc = lane&15, hi = lane>>4;
  f32x4 acc[2][2];
  #pragma unroll
  for (int i=0;i<2;i++)
    #pragma unroll
    for (int j=0;j<2;j++) acc[i][j] = (f32x4){0.f,0.f,0.f,0.f};

  const u16* plane = (wave==0) ? C.Ah : (wave==1) ? C.Al : (wave==2) ? C.Bh : C.Bl;
  long pstr = (wave<2) ? C.strA : C.strB;
  int rbase = (wave<2) ? m0 : n0;
  const u16* pb = plane + (long)bh*pstr;
  char* dstbase = smem + wave*4096;
  int srow = lane>>2, skq = lane&3;

  for (int k0=0; k0<256; k0+=32){
    #pragma unroll
    for (int ii=0; ii<4; ++ii){
      int row = ii*16 + srow;
      int kcs = k0 + ((skq ^ ((row>>1)&3))<<3);
      gload16(pb + (long)(rbase+row)*256 + kcs, dstbase + ii*1024);
    }
    __syncthreads();
    short8 aH[2], aL[2], bH[2], bL[2];
    #pragma unroll
    for (int i=0;i<2;i++){
      int ra = wr*32 + i*16 + lc;
      int ca = ((hi ^ ((ra>>1)&3)))*8;
      aH[i] = *(const short8*)&AsH[ra*32 + ca];
      aL[i] = *(const short8*)&AsL[ra*32 + ca];
      int rb = wc*32 + i*16 + lc;
      int cb = ((hi ^ ((rb>>1)&3)))*8;
      bH[i] = *(const short8*)&BsH[rb*32 + cb];
      bL[i] = *(const short8*)&BsL[rb*32 + cb];
    }
    #pragma unroll
    for (int i=0;i<2;i++)
      #pragma unroll
      for (int j=0;j<2;j++){
        acc[i][j] = __builtin_amdgcn_mfma_f32_16x16x32_bf16(aH[i], bH[j], acc[i][j], 0,0,0);
        acc[i][j] = __builtin_amdgcn_mfma_f32_16x16x32_bf16(aH[i], bL[j], acc[i][j], 0,0,0);
        acc[i][j] = __builtin_amdgcn_mfma_f32_16x16x32_bf16(aL[i], bH[j], acc[i][j], 0,0,0);
      }
    __syncthreads();
  }

  // epilogue: scalars (with E terms) -> padded LDS -> coalesced writes both orientations
  long eb = (long)bh*65536;
  #pragma unroll
  for (int i=0;i<2;i++)
    #pragma unroll
    for (int j=0;j<2;j++){
      int rg = wr*32 + i*16 + hi*4;
      int cg = wc*32 + j*16 + lc;
      #pragma unroll
      for (int r=0;r<4;r++){
        float val = C.sa*acc[i][j][r];
        long ei = eb + (long)(m0+rg+r)*256 + (n0+cg);
        if (C.E1h) val += C.s1*(bf2f(C.E1h[ei]) + bf2f(C.E1l[ei]));
        if (C.E2h) val += C.s2*(bf2f(C.E2h[ei]) + bf2f(C.E2l[ei]));
        T[(rg+r)*68 + cg] = val;
      }
    }
  __syncthreads();
  int rr = tid>>2, cc0 = (tid&3)*16;
  if (C.oBF){
    u16 tmp[16];
    #pragma unroll
    for (int m=0;m<16;m++) tmp[m] = f2bf(T[rr*68 + cc0 + m]);
    long ob = (long)bh*C.strO + (long)(m0+rr)*256 + n0 + cc0;
    *(uint4*)&C.oBF[ob] = *(uint4*)&tmp[0];
    *(uint4*)&C.oBF[ob+8] = *(uint4*)&tmp[8];
  } else {
    u16 th[16], tl[16];
    #pragma unroll
    for (int m=0;m<16;m++) hilo(T[rr*68 + cc0 + m], th[m], tl[m]);
    long ob = (long)bh*65536 + (long)(m0+rr)*256 + n0 + cc0;
    *(uint4*)&C.oNh[ob]   = *(uint4*)&th[0];
    *(uint4*)&C.oNh[ob+8] = *(uint4*)&th[8];
    *(uint4*)&C.oNl[ob]   = *(uint4*)&tl[0];
    *(uint4*)&C.oNl[ob+8] = *(uint4*)&tl[8];
    if (C.oTh){
      #pragma unroll
      for (int m=0;m<16;m++) hilo(T[(cc0+m)*68 + rr], th[m], tl[m]);
      long obt = (long)bh*65536 + (long)(n0+rr)*256 + m0 + cc0;
      *(uint4*)&C.oTh[obt]   = *(uint4*)&th[0];
      *(uint4*)&C.oTh[obt+8] = *(uint4*)&th[8];
      *(uint4*)&C.oTl[obt]   = *(uint4*)&tl[0];
      *(uint4*)&C.oTl[obt+8] = *(uint4*)&tl[8];
    }
  }
}

// ---------- v -> vt bf16 transpose ----------
__launch_bounds__(256)
__global__ void k_vt(const float* v, u16* vt){
  __shared__ float tile[32][68];
  int pt = blockIdx.x, bh = blockIdx.y, t = threadIdx.x;
  int p = t>>3, d0 = (t&7)*8;
  const float* src = v + ((long)bh*8192 + pt*32 + p)*64 + d0;
  float4 a = *(const float4*)src;
  float4 b = *(const float4*)(src+4);
  tile[p][d0+0]=a.x; tile[p][d0+1]=a.y; tile[p][d0+2]=a.z; tile[p][d0+3]=a.w;
  tile[p][d0+4]=b.x; tile[p][d0+5]=b.y; tile[p][d0+6]=b.z; tile[p][d0+7]=b.w;
  __syncthreads();
  int pos2 = (t&15)*2;
  #pragma unroll
  for (int ll=0; ll<4; ++ll){
    int d = (t>>4) + 16*ll;
    unsigned val = pk2(tile[pos2][d], tile[pos2+1][d]);
    *(unsigned*)&vt[((long)(bh*64 + d))*8192 + pt*32 + pos2] = val;
  }
}

// ---------- MFMA flash ----------
template<int OM>
__launch_bounds__(256)
__global__ void k_flash2(const float* Q, const float* K, const u16* VT,
                         float* op, float* ml, u16* hb,
                         int kvchunk, long qbh, long kbh, long vtbh, int vtrow){
  __shared__ __align__(16) u16 KT[64*64];
  __shared__ __align__(16) u16 VTs[64*64];
  __shared__ __align__(16) u16 Pb[4*16*72];
  int bh = blockIdx.y, qt = blockIdx.x, sk = (OM==0) ? blockIdx.z : 0;
  int t = threadIdx.x, w = t>>6, l = t&63;
  int lq = l&15, hi = l>>4;

  short8 qf[2];
  {
    const float* qp = Q + (long)bh*qbh + (long)(qt*64 + w*16 + lq)*64 + hi*8;
    #pragma unroll
    for (int kh=0; kh<2; ++kh){
      float4 f0 = *(const float4*)(qp + kh*32);
      float4 f1 = *(const float4*)(qp + kh*32 + 4);
      union { short8 s; uint4 u; } c;
      c.u.x = pk2(f0.x,f0.y); c.u.y = pk2(f0.z,f0.w);
      c.u.z = pk2(f1.x,f1.y); c.u.w = pk2(f1.z,f1.w);
      qf[kh] = c.s;
    }
  }
  float m_run = -1e30f, l_run = 0.f;
  f32x4 o[4];
  #pragma unroll
  for (int i=0;i<4;i++) o[i] = (f32x4){0.f,0.f,0.f,0.f};

  const float* kbase = K + (long)bh*kbh;
  const u16* vtbase = VT + (long)bh*vtbh;
  char* Pw = (char*)&Pb[w*16*72];
  int kv0 = sk*kvchunk;

  for (int p0 = kv0; p0 < kv0 + kvchunk; p0 += 64){
    {
      int r = w*16 + (l>>2), d0 = (l&3)*16;
      const float* kr = kbase + (long)(p0 + r)*64 + d0;
      float4 f0 = *(const float4*)(kr+0);
      float4 f1 = *(const float4*)(kr+4);
      float4 f2 = *(const float4*)(kr+8);
      float4 f3 = *(const float4*)(kr+12);
      float fv[16] = {f0.x,f0.y,f0.z,f0.w,f1.x,f1.y,f1.z,f1.w,
                      f2.x,f2.y,f2.z,f2.w,f3.x,f3.y,f3.z,f3.w};
      #pragma unroll
      for (int m=0;m<8;m++){
        int d = d0 + 2*m;
        int byte = (r*128 + d*2) ^ ((r&7)<<4);
        *(unsigned*)((char*)KT + byte) = pk2(fv[2*m], fv[2*m+1]);
      }
    }
    #pragma unroll
    for (int ii=0; ii<2; ++ii){
      int inst = w*2 + ii;
      int d = inst*8 + (l>>3);
      int srcoff = ((l&7)*16) ^ ((d&7)<<4);
      const char* src = (const char*)(vtbase + (long)d*vtrow + p0) + srcoff;
      gload16(src, (char*)VTs + inst*1024);
    }
    __syncthreads();
    f32x4 s[4];
    #pragma unroll
    for (int i=0;i<4;i++){
      s[i] = (f32x4){0.f,0.f,0.f,0.f};
      #pragma unroll
      for (int kh=0;kh<2;kh++){
        int kvr = i*16 + lq;
        int byte = (kvr*128 + hi*16 + kh*64) ^ ((kvr&7)<<4);
        short8 kf = *(const short8*)((const char*)KT + byte);
        s[i] = __builtin_amdgcn_mfma_f32_16x16x32_bf16(kf, qf[kh], s[i], 0,0,0);
      }
    }
    float tm = -1e30f;
    #pragma unroll
    for (int i=0;i<4;i++)
      #pragma unroll
      for (int r=0;r<4;r++) tm = fmaxf(tm, s[i][r]);
    tm = fmaxf(tm, __shfl_xor(tm, 16));
    tm = fmaxf(tm, __shfl_xor(tm, 32));
    float mnew = fmaxf(m_run, tm);
    float scale = __expf(m_run - mnew);
    float tsum = 0.f;
    #pragma unroll
    for (int i=0;i<4;i++)
      #pragma unroll
      for (int r=0;r<4;r++){ float e = __expf(s[i][r]-mnew); s[i][r]=e; tsum += e; }
    tsum += __shfl_xor(tsum, 16);
    tsum += __shfl_xor(tsum, 32);
    l_run = l_run*scale + tsum;
    m_run = mnew;
    #pragma unroll
    for (int i=0;i<4;i++)
      #pragma unroll
      for (int r=0;r<4;r++) o[i][r] *= scale;
    #pragma unroll
    for (int i=0;i<4;i++){
      int byte = lq*144 + (i*16 + hi*4)*2;
      *(unsigned*)(Pw + byte)     = pk2(s[i][0], s[i][1]);
      *(unsigned*)(Pw + byte + 4) = pk2(s[i][2], s[i][3]);
    }
    short8 pf[2];
    #pragma unroll
    for (int kh=0;kh<2;kh++)
      pf[kh] = *(const short8*)(Pw + lq*144 + hi*16 + kh*64);
    #pragma unroll
    for (int i=0;i<4;i++){
      #pragma unroll
      for (int kh=0;kh<2;kh++){
        int d = i*16 + lq;
        int byte = (d*128 + hi*16 + kh*64) ^ ((d&7)<<4);
        short8 vf = *(const short8*)((const char*)VTs + byte);
        o[i] = __builtin_amdgcn_mfma_f32_16x16x32_bf16(vf, pf[kh], o[i], 0,0,0);
      }
    }
    __syncthreads();
  }

  int qrow = qt*64 + w*16 + lq;
  if constexpr (OM == 0){
    long ob = ((long)(sk*16+bh)*256 + qrow)*64;
    #pragma unroll
    for (int i=0;i<4;i++)
      #pragma unroll
      for (int r=0;r<4;r++) op[ob + i*16 + hi*4 + r] = o[i][r];
    if (l < 16){
      long mi = ((long)(sk*16+bh)*256 + qt*64 + w*16 + l)*2;
      ml[mi] = m_run; ml[mi+1] = l_run;
    }
  } else {
    float invl = 1.f/l_run;
    long hb0 = ((long)bh*8192 + qrow)*64;
    #pragma unroll
    for (int i=0;i<4;i++)
      #pragma unroll
      for (int r=0;r<4;r++){
        long idx = hb0 + i*16 + hi*4 + r;
        hb[idx] = f2bf(bf2f(hb[idx]) + o[i][r]*invl);
      }
  }
}

// ---------- combine split-K flash partials -> w3T hi/lo planes ----------
__global__ void k_fcomb(const float* op, const float* ml, u16* w3Th, u16* w3Tl){
  int bh = blockIdx.y, rt = blockIdx.x, t = threadIdx.x;
  int row = rt*16 + (t>>4), d0 = (t&15)*4;
  float M = -1e30f;
  for (int s=0;s<16;s++) M = fmaxf(M, ml[(((long)(s*16+bh)*256)+row)*2]);
  float lt = 0.f;
  float4 o = {0,0,0,0};
  for (int s=0;s<16;s++){
    long base = ((long)(s*16+bh)*256)+row;
    float w = __expf(ml[base*2]-M);
    lt += ml[base*2+1]*w;
    float4 ov = *(const float4*)&op[base*64 + d0];
    o.x += ov.x*w; o.y += ov.y*w; o.z += ov.z*w; o.w += ov.w*w;
  }
  float inv = 1.f/lt;
  float vals[4] = {o.x*inv, o.y*inv, o.z*inv, o.w*inv};
  #pragma unroll
  for (int dd=0; dd<4; ++dd){
    u16 hi, lo; hilo(vals[dd], hi, lo);
    long idx = (long)bh*32768 + (long)(d0+dd)*256 + row;
    w3Th[idx]=hi; w3Tl[idx]=lo;
  }
}

// ---------- depthwise conv residual -> headsb ----------
__launch_bounds__(256)
__global__ void k_conv(const float* v, const float* cw, u16* heads){
  __shared__ float vsl[160][64];
  __shared__ float cws[33];
  int bh = blockIdx.y, pt = blockIdx.x, t = threadIdx.x;
  int hh = bh & 7;
  if (t < 33) cws[t] = cw[hh*33 + t];
  int p0 = pt*128;
  const float* vp = v + (long)bh*8192*64;
  for (int l=0;l<10;l++){
    int fidx = (l*256 + t)*4;
    int r = fidx>>6, c = fidx&63;
    int gp = p0 - 16 + r;
    if (gp>=0 && gp<8192){
      float4 a = *(const float4*)(vp + (long)gp*64 + c);
      vsl[r][c]=a.x; vsl[r][c+1]=a.y; vsl[r][c+2]=a.z; vsl[r][c+3]=a.w;
    } else {
      vsl[r][c]=0.f; vsl[r][c+1]=0.f; vsl[r][c+2]=0.f; vsl[r][c+3]=0.f;
    }
  }
  __syncthreads();
  int d = t & 63, pg = t >> 6;
  u16* hp = heads + ((long)bh*8192 + p0)*64;
  for (int pp=0; pp<32; pp++){
    int pl = pp*4 + pg;
    float acc = 0.f;
    #pragma unroll
    for (int tt=0; tt<33; tt++) acc += vsl[pl+tt][d]*cws[tt];
    hp[(long)pl*64 + d] = f2bf(acc);
  }
}

// ---------- final ----------
__global__ void k_final(const float* hbuf, const float* g, const float* bt,
                        const float* fw, const float* fb, float* outp){
  int b = blockIdx.x, t = threadIdx.x;
  __shared__ float red[4];
  __shared__ float sx[512];
  __shared__ float lg[4];
  const float* x = hbuf + ((long)b*8192+191)*512;
  float2 xv = *(const float2*)(x + t*2);
  float s = xv.x + xv.y;
  for (int off=32; off; off>>=1) s += __shfl_down(s,off,64);
  if ((t&63)==0) red[t>>6]=s;
  __syncthreads();
  float mean = (red[0]+red[1]+red[2]+red[3])*(1.f/512.f);
  __syncthreads();
  float d0 = xv.x-mean, d1 = xv.y-mean;
  float ssq = d0*d0 + d1*d1;
  for (int off=32; off; off>>=1) ssq += __shfl_down(ssq,off,64);
  if ((t&63)==0) red[t>>6]=ssq;
  __syncthreads();
  float rstd = rsqrtf((red[0]+red[1]+red[2]+red[3])*(1.f/512.f) + 1e-5f);
  sx[t*2]   = d0*rstd*g[t*2]   + bt[t*2];
  sx[t*2+1] = d1*rstd*g[t*2+1] + bt[t*2+1];
  __syncthreads();
  int c = t>>7, jj = t&127;
  float part = 0.f;
  for (int kk=jj; kk<512; kk+=128) part += sx[kk]*fw[(long)kk*2 + c];
  for (int off=1; off<64; off<<=1) part += __shfl_xor(part,off,64);
  if ((t&63)==0) lg[t>>6]=part;
  __syncthreads();
  if (t==0){
    float l0 = lg[0]+lg[1] + fb[0];
    float l1 = lg[2]+lg[3] + fb[1];
    float m = fmaxf(l0,l1);
    float e0 = __expf(l0-m), e1 = __expf(l1-m);
    float inv = 1.f/(e0+e1);
    outp[b*2+0]=l0; outp[b*2+1]=l1;
    outp[4+b*2+0]=e0*inv; outp[4+b*2+1]=e1*inv;
    outp[8+b]=(l1>l0) ? 1.f : 0.f;
  }
}

// ===================== host launch =====================
static NC mkc(const u16* Ah,const u16* Al,const u16* Bh,const u16* Bl,
              const u16* E1h,const u16* E1l,const u16* E2h,const u16* E2l,
              u16* oNh,u16* oNl,u16* oTh,u16* oTl,u16* oBF,
              long strA,long strB,long strO,float sa,float s1,float s2){
  NC c; c.Ah=Ah;c.Al=Al;c.Bh=Bh;c.Bl=Bl;c.E1h=E1h;c.E1l=E1l;c.E2h=E2h;c.E2l=E2l;
  c.oNh=oNh;c.oNl=oNl;c.oTh=oTh;c.oTl=oTl;c.oBF=oBF;
  c.strA=strA;c.strB=strB;c.strO=strO;c.sa=sa;c.s1=s1;c.s2=s2; return c;
}

extern "C" void kernel_launch(void* const* d_in, const int* in_sizes, int n_in,
                              void* d_out, int out_size, void* d_ws, size_t ws_size,
                              hipStream_t stream){
  (void)in_sizes; (void)n_in; (void)out_size; (void)ws_size;
  const long TOK = (long)2*8192*512;
  const long PL = 1048576;
  float* W    = (float*)d_ws;
  float* rc   = W;
  float* h    = W + 64;
  float* q    = h + TOK;
  float* k    = q + TOK;
  float* v    = k + TOK;
  u16*  xlnb  = (u16*)(v + TOK);
  u16*  zPl   = xlnb;
  u16*  headsb= xlnb + TOK;
  u16*  wT    = headsb + TOK;
  float* ql   = (float*)(wT + PL);
  float* kl   = ql + 262144;
  float* a2f  = kl + 262144;
  u16*  a2Nh  = (u16*)(a2f + 1048576);
  u16*  a2Nl  = a2Nh + PL;
  u16*  YNh   = a2Nl + PL;
  u16*  YNl   = YNh + PL;
  u16*  YTh   = YNl + PL;
  u16*  YTl   = YTh + PL;
  u16*  Gth   = YTl + PL;
  u16*  Gtl   = Gth + PL;
  u16*  PNh   = Gtl + PL;
  u16*  PNl   = PNh + PL;
  u16*  PTh   = PNl + PL;
  u16*  PTl   = PTh + PL;
  u16*  w3Th  = PTl + PL;
  u16*  w3Tl  = w3Th + 524288;
  u16*  zwT   = w3Tl + 524288;
  u16*  vt    = zwT + 262144;
  float* op   = v;
  float* ml   = a2f;

  u16* zN_h[2] = { zPl,        zPl + 4*PL };
  u16* zN_l[2] = { zPl + PL,   zPl + 5*PL };
  u16* zT_h[2] = { zPl + 2*PL, zPl + 6*PL };
  u16* zT_l[2] = { zPl + 3*PL, zPl + 7*PL };

  dim3 B(256);

  k_cls<<<dim3(2), B, 0, stream>>>((const float*)d_in[3], h);
  k_cvtT<<<dim3(16,32), B, 0, stream>>>((const float*)d_in[1], wT, 1024, 512);
  k_gemm<0><<<dim3(125,4), B, 0, stream>>>(d_in[0], wT, (const float*)d_in[2],
                                           h, nullptr,nullptr,nullptr, 16000,512,1024);

  for (int blk=0; blk<2; ++blk){
    const float* lng  = (const float*)d_in[blk?10:4];
    const float* lnb  = (const float*)d_in[blk?11:5];
    const float* qkvw = (const float*)d_in[blk?12:6];
    const float* outw = (const float*)d_in[blk?13:7];
    const float* outb = (const float*)d_in[blk?14:8];
    const float* cw   = (const float*)d_in[blk?15:9];

    k_ln<<<dim3(16384), B, 0, stream>>>(h, lng, lnb, xlnb);

    k_cvtT<<<dim3(48,16), B, 0, stream>>>(qkvw, wT, 512, 1536);
    k_gemm<1><<<dim3(128,12), B, 0, stream>>>(xlnb, wT, nullptr,
                                              nullptr, q,k,v, 16384,1536,512);

    k_landmark<<<dim3(256,16), dim3(64), 0, stream>>>(q, ql);
    k_landmark<<<dim3(256,16), dim3(64), 0, stream>>>(k, kl);

    k_vt<<<dim3(256,16), B, 0, stream>>>(v, vt);
    k_conv<<<dim3(64,16), B, 0, stream>>>(v, cw, headsb);

    k_a2<<<dim3(16,16), B, 0, stream>>>(ql, kl, a2f, a2Nh, a2Nl);
    k_colrow<<<dim3(16), B, 0, stream>>>(a2f, rc);
    k_denom<<<dim3(1), dim3(1), 0, stream>>>(rc, rc+32);
    k_z0p<<<dim3(8,8,16), B, 0, stream>>>(a2f, rc+32, zN_h[0],zN_l[0],zT_h[0],zT_l[0]);

    for (int it=0; it<6; ++it){
      int zi = it&1, zo = (it+1)&1;
      // S1: Y = a2@z  (A=a2, B=zT -> a2@(zT)^T), dual out Y,Y^T
      NC s1 = mkc(a2Nh,a2Nl, zT_h[zi],zT_l[zi], nullptr,nullptr,nullptr,nullptr,
                  YNh,YNl, YTh,YTl, nullptr, 65536,65536,0, 1.f,0.f,0.f);
      k_nmm<<<dim3(4,4,16), B, 0, stream>>>(s1, s1);
      // S2 op0: G^T = 7*Y^T - Y^T@Y^T  (A=YT, B=YN)
      NC s2a = mkc(YTh,YTl, YNh,YNl, YTh,YTl, nullptr,nullptr,
                   Gth,Gtl, nullptr,nullptr, nullptr, 65536,65536,0, -1.f,7.f,0.f);
      // S2 op1: P = z@Y  (A=zN, B=YT), dual out P,P^T
      NC s2b = mkc(zN_h[zi],zN_l[zi], YTh,YTl, nullptr,nullptr,nullptr,nullptr,
                   PNh,PNl, PTh,PTl, nullptr, 65536,65536,0, 1.f,0.f,0.f);
      k_nmm<<<dim3(4,4,32), B, 0, stream>>>(s2a, s2b);
      // S3: z' = 0.25*P@G + 3.25*z - 3.75*P  (A=PN, B=Gt), dual out z',z'^T
      NC s3 = mkc(PNh,PNl, Gth,Gtl, zN_h[zi],zN_l[zi], PNh,PNl,
                  zN_h[zo],zN_l[zo], zT_h[zo],zT_l[zo], nullptr,
                  65536,65536,0, 0.25f,3.25f,-3.75f);
      k_nmm<<<dim3(4,4,16), B, 0, stream>>>(s3, s3);
    }

    // a3: w3 = softmax(q_l @ k^T) @ v  (split-K 16 chunks of 512) -> w3T planes
    k_flash2<0><<<dim3(4,16,16), B, 0, stream>>>(ql, k, vt, op, ml, nullptr,
                                                 512, 16384L, 524288L, 524288L, 8192);
    k_fcomb<<<dim3(16,16), B, 0, stream>>>(op, ml, w3Th, w3Tl);
    // zw^T = w3^T @ z^T = (z@w3)^T  (A=w3T strA=32768, B=zN[0]) -> bf16
    NC zwc = mkc(w3Th,w3Tl, zN_h[0],zN_l[0], nullptr,nullptr,nullptr,nullptr,
                 nullptr,nullptr,nullptr,nullptr, zwT, 32768,65536,16384, 1.f,0.f,0.f);
    k_nmm<<<dim3(1,4,16), B, 0, stream>>>(zwc, zwc);
    // a1: headsb += softmax(q @ k_l^T) @ zw
    k_flash2<1><<<dim3(128,16,1), B, 0, stream>>>(q, kl, zwT, nullptr, nullptr, headsb,
                                                  256, 524288L, 16384L, 16384L, 256);

    k_cvtT<<<dim3(16,16), B, 0, stream>>>(outw, wT, 512, 512);
    k_gemm<2><<<dim3(128,4), B, 0, stream>>>(headsb, wT, outb,
                                             h, nullptr,nullptr,nullptr, 16384,512,512);
  }

  k_final<<<dim3(2), B, 0, stream>>>(h, (const float*)d_in[16], (const float*)d_in[17],
                                     (const float*)d_in[18], (const float*)d_in[19], (float*)d_out);
}